// Round 13
// baseline (144.224 us; speedup 1.0000x reference)
//
#include <hip/hip_runtime.h>
#include <stdint.h>

#define NN 100000
#define NE 1600000
#define C  128
#define NB 782          // buckets of 128 dst nodes: 782*128 = 100096 >= NN
#define CAP 4096        // per-bucket edge capacity (mean 2048, sigma ~45)
#define SB_SHIFT 13     // src coarse-slice key in phase2 sort
#define MB 782          // front GEMM blocks: 128 rows each (512 thr)
#define P1B 250         // phase1 blocks (6400 edges each, 512 thr)
#define MBO 782         // gemm_out blocks: 128 rows each (512 thr)

typedef __attribute__((ext_vector_type(8))) short short8;
typedef __attribute__((ext_vector_type(4))) float f32x4;

__device__ __forceinline__ float bf2f(uint16_t u) {
  union { uint32_t u; float f; } v; v.u = ((uint32_t)u) << 16; return v.f;
}
__device__ __forceinline__ uint16_t f2bf(float f) {
  union { float f; uint32_t u; } v; v.f = f;
  uint32_t r = v.u + 0x7fffu + ((v.u >> 16) & 1u);   // RNE
  return (uint16_t)(r >> 16);
}
__device__ __forceinline__ float2 bf2x2(uint32_t u) {
  return make_float2(bf2f((uint16_t)u), bf2f((uint16_t)(u >> 16)));
}
__device__ __forceinline__ short8 cvt_row8(const float* p) {
  float4 u = *(const float4*)p;
  float4 v = *(const float4*)(p + 4);
  short8 av;
  av[0] = (short)f2bf(u.x); av[1] = (short)f2bf(u.y);
  av[2] = (short)f2bf(u.z); av[3] = (short)f2bf(u.w);
  av[4] = (short)f2bf(v.x); av[5] = (short)f2bf(v.y);
  av[6] = (short)f2bf(v.z); av[7] = (short)f2bf(v.w);
  return av;
}

// ---------------- cast the 3 weight matrices in one dispatch ----------------
__global__ __launch_bounds__(256) void cast3_k(
    const float* __restrict__ a, const float* __restrict__ b, const float* __restrict__ c,
    uint16_t* __restrict__ oa, uint16_t* __restrict__ ob, uint16_t* __restrict__ oc)
{
  int i = blockIdx.x * 256 + threadIdx.x;     // 3 * 4096 float4-groups
  int which = i >> 12, j = i & 4095;
  const float* s = which == 0 ? a : (which == 1 ? b : c);
  uint16_t* d    = which == 0 ? oa : (which == 1 ? ob : oc);
  float4 v = ((const float4*)s)[j];
  uint2 p;
  p.x = (uint32_t)f2bf(v.x) | ((uint32_t)f2bf(v.y) << 16);
  p.y = (uint32_t)f2bf(v.z) | ((uint32_t)f2bf(v.w) << 16);
  ((uint2*)d)[j] = p;
}

// LDS weight tile: chunk (c, k16) at byte c*256 + ((k16^(c&15))<<4).
// MFMA operands SWAPPED (weights as A, x as B): lane (g,r16) holds
// out[row=tile_m+r16][cols nt*16+g*4 .. +3].
// Front output staging: after MFMA the Wp tile is dead; LDS reused as h-tile
// (128 x 256B, 16B-slot XOR swizzle (row&15)<<4); final stores are 512thr x
// uint4 full-line writes (kills write amplification).

// ------- fused front: blocks [0,MB) = Wp GEMM; [MB,MB+P1B) = phase1 ---------
__global__ __launch_bounds__(512) void fused_front_k(
    const float* __restrict__ x, const uint16_t* __restrict__ wpb,
    const float* __restrict__ bp, uint16_t* __restrict__ h,
    const int* __restrict__ esrc, const int* __restrict__ edst,
    int* __restrict__ gcnt, uint32_t* __restrict__ ebuf)
{
  extern __shared__ uint8_t slds[];
  const int t = threadIdx.x;

  if (blockIdx.x < MB) {
    // ---------------- GEMM role: h = relu(x @ Wp^T + bp) ----------------
#pragma unroll
    for (int qq = 0; qq < 4; ++qq) {          // stage Wp: 2048 chunks of 16B
      int ci = qq * 512 + t;
      int cl = ci >> 4, k16 = ci & 15;
      *(short8*)(slds + cl * 256 + ((k16 ^ (cl & 15)) << 4)) =
          *(const short8*)(wpb + ci * 8);
    }
    __syncthreads();

    const int w = t >> 6, lane = t & 63;
    const int tile_m0 = blockIdx.x * 128;
    const int r16 = lane & 15, g = lane >> 4;
    const int row = tile_m0 + w * 16 + r16;
    const int arow = row < NN ? row : NN - 1; // clamp OOB read (no early return)

    short8 a[4];
    const float* xp = x + (size_t)arow * C + g * 8;
#pragma unroll
    for (int kk = 0; kk < 4; ++kk) a[kk] = cvt_row8(xp + kk * 32);

    f32x4 hp[8];
#pragma unroll
    for (int nt = 0; nt < 8; ++nt) {
      f32x4 p = {0.f, 0.f, 0.f, 0.f};
      const int cidx = nt * 16 + r16;
      const uint8_t* rbp = slds + cidx * 256;
#pragma unroll
      for (int kk = 0; kk < 4; ++kk) {
        int slot = (((kk << 2) + g) ^ (cidx & 15)) << 4;
        p = __builtin_amdgcn_mfma_f32_16x16x32_bf16(*(const short8*)(rbp + slot), a[kk], p, 0, 0, 0);
      }
      hp[nt] = p;
    }
    __syncthreads();                          // Wp dead; reuse LDS as h-tile

    const int lrow = w * 16 + r16;            // 0..127
#pragma unroll
    for (int nt = 0; nt < 8; ++nt) {
      const int col0 = nt * 16 + g * 4;
      float4 bp4 = *(const float4*)(bp + col0);
      float h0 = hp[nt][0] + bp4.x, h1 = hp[nt][1] + bp4.y;
      float h2 = hp[nt][2] + bp4.z, h3 = hp[nt][3] + bp4.w;
      h0 = h0 > 0.f ? h0 : 0.f; h1 = h1 > 0.f ? h1 : 0.f;
      h2 = h2 > 0.f ? h2 : 0.f; h3 = h3 > 0.f ? h3 : 0.f;
      uint2 ph;
      ph.x = (uint32_t)f2bf(h0) | ((uint32_t)f2bf(h1) << 16);
      ph.y = (uint32_t)f2bf(h2) | ((uint32_t)f2bf(h3) << 16);
      *(uint2*)(slds + lrow * 256 + ((col0 * 2) ^ ((lrow & 15) << 4))) = ph;
    }
    __syncthreads();

    // full-line stores: 4 x (512 thr x 16B = 8KB) = 32KB tile
#pragma unroll
    for (int i = 0; i < 4; ++i) {
      const int ofs = i * 8192 + t * 16;
      const int trow = ofs >> 8;
      const int inrow = ofs & 255;
      const int grow = tile_m0 + trow;
      if (grow < NN)
        *(uint4*)(h + (size_t)grow * C + (inrow >> 1)) =
            *(const uint4*)(slds + (trow << 8) + (inrow ^ ((trow & 15) << 4)));
    }
  } else {
    // ---------------- phase1 role: bucket edges by dst>>7 ----------------
    int* bh = (int*)slds;                     // NB ints: histogram / cursor
    int* gb = bh + NB;                        // NB ints: reserved base
    const int blk = blockIdx.x - MB;
    const int base = blk * 6400;              // 1600 int4 per block

    for (int i = t; i < NB; i += 512) bh[i] = 0;

    const int4* ed4 = (const int4*)(edst + base);
    const int4* es4 = (const int4*)(esrc + base);
    int4 dv[4], sv[4];
    bool val[4];
#pragma unroll
    for (int k = 0; k < 4; ++k) {
      int i = t + k * 512;
      val[k] = (i < 1600);
      if (val[k]) { dv[k] = ed4[i]; sv[k] = es4[i]; }
    }
    __syncthreads();

#pragma unroll
    for (int k = 0; k < 4; ++k) if (val[k]) {
      atomicAdd(&bh[dv[k].x >> 7], 1); atomicAdd(&bh[dv[k].y >> 7], 1);
      atomicAdd(&bh[dv[k].z >> 7], 1); atomicAdd(&bh[dv[k].w >> 7], 1);
    }
    __syncthreads();

    for (int i = t; i < NB; i += 512) {
      int c = bh[i];
      gb[i] = c ? atomicAdd(&gcnt[i], c) : 0;
      bh[i] = 0;                              // reuse as local cursor
    }
    __syncthreads();

#define P1_SCATTER(d, s) do { \
      int bb = (d) >> 7; \
      int o = atomicAdd(&bh[bb], 1); \
      int pos = gb[bb] + o; \
      if (pos < CAP) ebuf[(size_t)bb * CAP + pos] = ((uint32_t)((d) & 127) << 17) | (uint32_t)(s); \
    } while (0)

#pragma unroll
    for (int k = 0; k < 4; ++k) if (val[k]) {
      P1_SCATTER(dv[k].x, sv[k].x); P1_SCATTER(dv[k].y, sv[k].y);
      P1_SCATTER(dv[k].z, sv[k].z); P1_SCATTER(dv[k].w, sv[k].w);
    }
#undef P1_SCATTER
  }
}

// ------- phase 2: inlined bucket-scan + per-bucket LDS sort -----------------
__global__ __launch_bounds__(256) void phase2_k(
    const uint32_t* __restrict__ ebuf, const int* __restrict__ gcnt,
    int* __restrict__ ssrc, int2* __restrict__ sdeg)
{
  __shared__ uint32_t raw[CAP];
  __shared__ int lout[CAP];
  __shared__ int cnt2[128 * 16];
  __shared__ int nd[128];
  __shared__ int psum[256];
  const int b = blockIdx.x, t = threadIdx.x;
  const int n0 = b * 128;

  // inline exclusive scan: base = sum gcnt[0..b)
  int acc = 0;
  for (int i = t; i < b; i += 256) acc += gcnt[i];
  psum[t] = acc;
  __syncthreads();
  for (int off = 128; off > 0; off >>= 1) {
    if (t < off) psum[t] += psum[t + off];
    __syncthreads();
  }
  const int base = psum[0];
  int cnt = gcnt[b]; if (cnt > CAP) cnt = CAP;

  for (int i = t; i < 128 * 16; i += 256) cnt2[i] = 0;
  __syncthreads();
  for (int i = t; i < cnt; i += 256) {
    uint32_t v = ebuf[(size_t)b * CAP + i];
    raw[i] = v;
    atomicAdd(&cnt2[(v >> 17) * 16 + ((v & 0x1FFFFu) >> SB_SHIFT)], 1);
  }
  __syncthreads();

  int deg_t = 0;
  if (t < 128) {
#pragma unroll
    for (int i = 0; i < 16; ++i) deg_t += cnt2[t * 16 + i];
    nd[t] = deg_t;
  }
  __syncthreads();
  for (int off = 1; off < 128; off <<= 1) {
    int v = 0;
    if (t < 128 && t >= off) v = nd[t - off];
    __syncthreads();
    if (t < 128) nd[t] += v;
    __syncthreads();
  }
  if (t < 128) {
    int pref = nd[t] - deg_t;               // exclusive within bucket
    if (n0 + t < NN) sdeg[n0 + t] = make_int2(base + pref, deg_t);
    int run = pref;
#pragma unroll
    for (int i = 0; i < 16; ++i) { int c = cnt2[t * 16 + i]; cnt2[t * 16 + i] = run; run += c; }
  }
  __syncthreads();
  for (int i = t; i < cnt; i += 256) {
    uint32_t v = raw[i];
    int o = atomicAdd(&cnt2[(v >> 17) * 16 + ((v & 0x1FFFFu) >> SB_SHIFT)], 1);
    lout[o] = (int)(v & 0x1FFFFu);
  }
  __syncthreads();
  for (int i = t; i < cnt; i += 256) ssrc[base + i] = lout[i];
}

// ------- aggregation: 1 wave/node, 16-lane edge groups --------------------
// Main loop unpredicated (full 16-edge batches); clamped+predicated tail.
__global__ __launch_bounds__(256) void aggregate_k(
    const uint16_t* __restrict__ h, const int* __restrict__ ssrc,
    const int2* __restrict__ sdeg, uint16_t* __restrict__ agg)
{
  const int wid = (blockIdx.x * 256 + threadIdx.x) >> 6;
  if (wid >= NN) return;
  const int lane = threadIdx.x & 63;
  const int q = lane >> 4;            // edge slot within group of 4
  const int l16 = lane & 15;          // channels l16*8 .. l16*8+7
  const int2 sd = sdeg[wid];
  const int s0 = sd.x, cnt = sd.y;
  const size_t choff = (size_t)l16 * 8;
  float2 a0 = {0.f, 0.f}, a1 = {0.f, 0.f}, a2 = {0.f, 0.f}, a3 = {0.f, 0.f};

#define ACC8(v) do { \
    a0 += bf2x2((v).x); a1 += bf2x2((v).y); \
    a2 += bf2x2((v).z); a3 += bf2x2((v).w); \
  } while (0)

  int j = 0;
  if (cnt >= 16) {
    int e0 = ssrc[s0 + q];
    int e1 = ssrc[s0 + 4 + q];
    int e2 = ssrc[s0 + 8 + q];
    int e3 = ssrc[s0 + 12 + q];
    for (; j + 16 <= cnt;) {
      uint4 v0 = *(const uint4*)(h + (size_t)e0 * C + choff);
      uint4 v1 = *(const uint4*)(h + (size_t)e1 * C + choff);
      uint4 v2 = *(const uint4*)(h + (size_t)e2 * C + choff);
      uint4 v3 = *(const uint4*)(h + (size_t)e3 * C + choff);
      j += 16;
      if (j + 16 <= cnt) {            // prefetch next indices under the gathers
        e0 = ssrc[s0 + j + q];
        e1 = ssrc[s0 + j + 4 + q];
        e2 = ssrc[s0 + j + 8 + q];
        e3 = ssrc[s0 + j + 12 + q];
      }
      ACC8(v0); ACC8(v1); ACC8(v2); ACC8(v3);   // no predication
    }
  }
  const int rem = cnt - j;            // 0..15 tail, clamped + predicated
  if (rem > 0) {
    int i0 = j + ((q      < rem) ? q      : 0);
    int i1 = j + ((q + 4  < rem) ? q + 4  : 0);
    int i2 = j + ((q + 8  < rem) ? q + 8  : 0);
    int i3 = j + ((q + 12 < rem) ? q + 12 : 0);
    int e0 = ssrc[s0 + i0];
    int e1 = ssrc[s0 + i1];
    int e2 = ssrc[s0 + i2];
    int e3 = ssrc[s0 + i3];
    uint4 v0 = *(const uint4*)(h + (size_t)e0 * C + choff);
    uint4 v1 = *(const uint4*)(h + (size_t)e1 * C + choff);
    uint4 v2 = *(const uint4*)(h + (size_t)e2 * C + choff);
    uint4 v3 = *(const uint4*)(h + (size_t)e3 * C + choff);
    if (q < rem)      ACC8(v0);
    if (q + 4 < rem)  ACC8(v1);
    if (q + 8 < rem)  ACC8(v2);
    if (q + 12 < rem) ACC8(v3);
  }
#undef ACC8

#pragma unroll
  for (int msk = 16; msk <= 32; msk <<= 1) {
    a0.x += __shfl_xor(a0.x, msk, 64); a0.y += __shfl_xor(a0.y, msk, 64);
    a1.x += __shfl_xor(a1.x, msk, 64); a1.y += __shfl_xor(a1.y, msk, 64);
    a2.x += __shfl_xor(a2.x, msk, 64); a2.y += __shfl_xor(a2.y, msk, 64);
    a3.x += __shfl_xor(a3.x, msk, 64); a3.y += __shfl_xor(a3.y, msk, 64);
  }
  if (q == 0) {
    uint4 p;
    p.x = (uint32_t)f2bf(a0.x) | ((uint32_t)f2bf(a0.y) << 16);
    p.y = (uint32_t)f2bf(a1.x) | ((uint32_t)f2bf(a1.y) << 16);
    p.z = (uint32_t)f2bf(a2.x) | ((uint32_t)f2bf(a2.y) << 16);
    p.w = (uint32_t)f2bf(a3.x) | ((uint32_t)f2bf(a3.y) << 16);
    *(uint4*)(agg + (size_t)wid * C + choff) = p;
  }
}

// ------- gemm_out: out = LN(agg@Wl^T + x@Wr^T + bl)*gamma + beta ------------
// Wl+Wr in 64KB LDS; x read as f32 and converted in-register (no rb buffer).
// Swapped-D layout -> float4 full-line out stores; LN across 4 lanes.
__global__ __launch_bounds__(512) void gemm_out_k(
    const uint16_t* __restrict__ aggb, const float* __restrict__ x,
    const uint16_t* __restrict__ wlb, const uint16_t* __restrict__ wrb,
    const float* __restrict__ bl, const float* __restrict__ gamma,
    const float* __restrict__ beta, float* __restrict__ out)
{
  extern __shared__ uint8_t slds[];
  const int t = threadIdx.x;
#pragma unroll
  for (int qq = 0; qq < 8; ++qq) {            // stage Wl at 0, Wr at +32KB
    int ci = qq * 512 + t;                    // 0..4095
    int m  = ci >> 11;
    int cj = ci & 2047;
    int cl = cj >> 4, k16 = cj & 15;
    const uint16_t* wsrc = m == 0 ? wlb : wrb;
    *(short8*)(slds + m * 32768 + cl * 256 + ((k16 ^ (cl & 15)) << 4)) =
        *(const short8*)(wsrc + cj * 8);
  }
  __syncthreads();

  const int w = t >> 6, lane = t & 63;
  const int tile_m = blockIdx.x * 128 + w * 16;
  if (tile_m >= NN) return;
  const int r16 = lane & 15, g = lane >> 4;

  const int row = tile_m + r16;
  const int arow = row < NN ? row : NN - 1;   // clamp OOB read
  short8 a0[4], a1[4];
  const uint16_t* p0 = aggb + (size_t)arow * C + g * 8;
  const float* xp = x + (size_t)arow * C + g * 8;
#pragma unroll
  for (int kk = 0; kk < 4; ++kk) {
    a0[kk] = *(const short8*)(p0 + kk * 32);
    a1[kk] = cvt_row8(xp + kk * 32);
  }

  f32x4 acc[8];
  float s1 = 0.f, s2 = 0.f;
#pragma unroll
  for (int nt = 0; nt < 8; ++nt) {
    f32x4 c4 = {0.f, 0.f, 0.f, 0.f};
    const int c = nt * 16 + r16;
    const uint8_t* rbl = slds + c * 256;
    const uint8_t* rbr = slds + 32768 + c * 256;
#pragma unroll
    for (int kk = 0; kk < 4; ++kk) {
      int slot = (((kk << 2) + g) ^ (c & 15)) << 4;
      c4 = __builtin_amdgcn_mfma_f32_16x16x32_bf16(*(const short8*)(rbl + slot), a0[kk], c4, 0, 0, 0);
      c4 = __builtin_amdgcn_mfma_f32_16x16x32_bf16(*(const short8*)(rbr + slot), a1[kk], c4, 0, 0, 0);
    }
    const int col0 = nt * 16 + g * 4;
    float4 bl4 = *(const float4*)(bl + col0);
    c4[0] += bl4.x; c4[1] += bl4.y; c4[2] += bl4.z; c4[3] += bl4.w;
#pragma unroll
    for (int rr = 0; rr < 4; ++rr) { s1 += c4[rr]; s2 += c4[rr] * c4[rr]; }
    acc[nt] = c4;
  }

  // LN reduce across the 4 g-groups holding this row (lanes r16+16k)
  s1 += __shfl_xor(s1, 16, 64); s2 += __shfl_xor(s2, 16, 64);
  s1 += __shfl_xor(s1, 32, 64); s2 += __shfl_xor(s2, 32, 64);
  const float mean = s1 * (1.f / C);
  const float var = s2 * (1.f / C) - mean * mean;
  const float rstd = rsqrtf(var + 1e-5f);

  if (row < NN) {
#pragma unroll
    for (int nt = 0; nt < 8; ++nt) {
      const int col0 = nt * 16 + g * 4;
      float4 gm = *(const float4*)(gamma + col0);
      float4 bt = *(const float4*)(beta + col0);
      float4 o;
      o.x = (acc[nt][0] - mean) * rstd * gm.x + bt.x;
      o.y = (acc[nt][1] - mean) * rstd * gm.y + bt.y;
      o.z = (acc[nt][2] - mean) * rstd * gm.z + bt.z;
      o.w = (acc[nt][3] - mean) * rstd * gm.w + bt.w;
      *(float4*)(out + (size_t)row * C + col0) = o;   // 16B coalesced store
    }
  }
}

// ---------------- launch ----------------
extern "C" void kernel_launch(void* const* d_in, const int* in_sizes, int n_in,
                              void* d_out, int out_size, void* d_ws, size_t ws_size,
                              hipStream_t stream)
{
  const float* x        = (const float*)d_in[0];
  const int* ei         = (const int*)d_in[1];     // int32 from harness
  const float* Wp       = (const float*)d_in[2];
  const float* bp       = (const float*)d_in[3];
  const float* Wl       = (const float*)d_in[4];
  const float* bl       = (const float*)d_in[5];
  const float* Wr       = (const float*)d_in[6];
  const float* gamma    = (const float*)d_in[7];
  const float* beta     = (const float*)d_in[8];
  float* out            = (float*)d_out;

  char* ws = (char*)d_ws;
  uint16_t* h    = (uint16_t*)(ws + 0);          // 25,600,000  relu(proj) bf16
  uint32_t* ebuf = (uint32_t*)(ws + 25600000);   // 12,812,288  bucketed edges
  uint16_t* aggb = (uint16_t*)(ws + 25600000);   // 25,600,000  ALIASES ebuf (dead by aggregate)
  uint16_t* wpb  = (uint16_t*)(ws + 76800000);   // 32,768
  uint16_t* wlb  = (uint16_t*)(ws + 76832768);   // 32,768
  uint16_t* wrb  = (uint16_t*)(ws + 76865536);   // 32,768
  int2* sdeg     = (int2*)(ws + 76898304);       // 800,000  {start, deg} per node
  int* gcnt      = (int*)(ws + 77698304);        // 3,128
  int* ssrc      = (int*)(ws + 78102400);        // 6,400,000

  const int* esrc = ei;        // edge_index[0]
  const int* edst = ei + NE;   // edge_index[1]

  hipMemsetAsync(gcnt, 0, NB * sizeof(int), stream);

  cast3_k<<<48, 256, 0, stream>>>(Wp, Wl, Wr, wpb, wlb, wrb);

  fused_front_k<<<MB + P1B, 512, 32768, stream>>>(
      x, wpb, bp, h, esrc, edst, gcnt, ebuf);

  phase2_k<<<NB, 256, 0, stream>>>(ebuf, gcnt, ssrc, sdeg);

  aggregate_k<<<(NN + 3) / 4, 256, 0, stream>>>(h, ssrc, sdeg, aggb);

  gemm_out_k<<<MBO, 512, 65536, stream>>>(aggb, x, wlb, wrb, bl, gamma, beta, out);
}

// Round 14
// 138.075 us; speedup vs baseline: 1.0445x; 1.0445x over previous
//
#include <hip/hip_runtime.h>
#include <stdint.h>

#define NN 100000
#define NE 1600000
#define C  128
#define NB 782          // buckets of 128 dst nodes: 782*128 = 100096 >= NN
#define CAP 4096        // per-bucket edge capacity (mean 2048, sigma ~45)
#define SB_SHIFT 13     // src coarse-slice key in bucket sort
#define MB 782          // front GEMM blocks: 128 rows each (512 thr)
#define P1B 250         // phase1 blocks (6400 edges each, 512 thr)
#define MBO 782         // gemm_out blocks: 128 rows each (512 thr)

typedef __attribute__((ext_vector_type(8))) short short8;
typedef __attribute__((ext_vector_type(4))) float f32x4;

__device__ __forceinline__ float bf2f(uint16_t u) {
  union { uint32_t u; float f; } v; v.u = ((uint32_t)u) << 16; return v.f;
}
__device__ __forceinline__ uint16_t f2bf(float f) {
  union { float f; uint32_t u; } v; v.f = f;
  uint32_t r = v.u + 0x7fffu + ((v.u >> 16) & 1u);   // RNE
  return (uint16_t)(r >> 16);
}
__device__ __forceinline__ float2 bf2x2(uint32_t u) {
  return make_float2(bf2f((uint16_t)u), bf2f((uint16_t)(u >> 16)));
}
__device__ __forceinline__ short8 cvt_row8(const float* p) {
  float4 u = *(const float4*)p;
  float4 v = *(const float4*)(p + 4);
  short8 av;
  av[0] = (short)f2bf(u.x); av[1] = (short)f2bf(u.y);
  av[2] = (short)f2bf(u.z); av[3] = (short)f2bf(u.w);
  av[4] = (short)f2bf(v.x); av[5] = (short)f2bf(v.y);
  av[6] = (short)f2bf(v.z); av[7] = (short)f2bf(v.w);
  return av;
}

// ---------------- cast the 3 weight matrices in one dispatch ----------------
__global__ __launch_bounds__(256) void cast3_k(
    const float* __restrict__ a, const float* __restrict__ b, const float* __restrict__ c,
    uint16_t* __restrict__ oa, uint16_t* __restrict__ ob, uint16_t* __restrict__ oc)
{
  int i = blockIdx.x * 256 + threadIdx.x;     // 3 * 4096 float4-groups
  int which = i >> 12, j = i & 4095;
  const float* s = which == 0 ? a : (which == 1 ? b : c);
  uint16_t* d    = which == 0 ? oa : (which == 1 ? ob : oc);
  float4 v = ((const float4*)s)[j];
  uint2 p;
  p.x = (uint32_t)f2bf(v.x) | ((uint32_t)f2bf(v.y) << 16);
  p.y = (uint32_t)f2bf(v.z) | ((uint32_t)f2bf(v.w) << 16);
  ((uint2*)d)[j] = p;
}

// LDS weight tile: chunk (c, k16) at byte c*256 + ((k16^(c&15))<<4).
// MFMA operands SWAPPED (weights as A, x as B): lane (g,r16) holds
// out[row=tile_m+r16][cols nt*16+g*4 .. +3].

// ------- fused front: blocks [0,MB) = Wp GEMM; [MB,MB+P1B) = phase1 ---------
__global__ __launch_bounds__(512) void fused_front_k(
    const float* __restrict__ x, const uint16_t* __restrict__ wpb,
    const float* __restrict__ bp, uint16_t* __restrict__ h,
    const int* __restrict__ esrc, const int* __restrict__ edst,
    int* __restrict__ gcnt, uint32_t* __restrict__ ebuf)
{
  extern __shared__ uint8_t slds[];
  const int t = threadIdx.x;

  if (blockIdx.x < MB) {
    // ---------------- GEMM role: h = relu(x @ Wp^T + bp) ----------------
#pragma unroll
    for (int qq = 0; qq < 4; ++qq) {          // stage Wp: 2048 chunks of 16B
      int ci = qq * 512 + t;
      int cl = ci >> 4, k16 = ci & 15;
      *(short8*)(slds + cl * 256 + ((k16 ^ (cl & 15)) << 4)) =
          *(const short8*)(wpb + ci * 8);
    }
    __syncthreads();

    const int w = t >> 6, lane = t & 63;
    const int tile_m0 = blockIdx.x * 128;
    const int r16 = lane & 15, g = lane >> 4;
    const int row = tile_m0 + w * 16 + r16;
    const int arow = row < NN ? row : NN - 1; // clamp OOB read (no early return)

    short8 a[4];
    const float* xp = x + (size_t)arow * C + g * 8;
#pragma unroll
    for (int kk = 0; kk < 4; ++kk) a[kk] = cvt_row8(xp + kk * 32);

    f32x4 hp[8];
#pragma unroll
    for (int nt = 0; nt < 8; ++nt) {
      f32x4 p = {0.f, 0.f, 0.f, 0.f};
      const int cidx = nt * 16 + r16;
      const uint8_t* rbp = slds + cidx * 256;
#pragma unroll
      for (int kk = 0; kk < 4; ++kk) {
        int slot = (((kk << 2) + g) ^ (cidx & 15)) << 4;
        p = __builtin_amdgcn_mfma_f32_16x16x32_bf16(*(const short8*)(rbp + slot), a[kk], p, 0, 0, 0);
      }
      hp[nt] = p;
    }
    __syncthreads();                          // Wp dead; reuse LDS as h-tile

    const int lrow = w * 16 + r16;            // 0..127
#pragma unroll
    for (int nt = 0; nt < 8; ++nt) {
      const int col0 = nt * 16 + g * 4;
      float4 bp4 = *(const float4*)(bp + col0);
      float h0 = hp[nt][0] + bp4.x, h1 = hp[nt][1] + bp4.y;
      float h2 = hp[nt][2] + bp4.z, h3 = hp[nt][3] + bp4.w;
      h0 = h0 > 0.f ? h0 : 0.f; h1 = h1 > 0.f ? h1 : 0.f;
      h2 = h2 > 0.f ? h2 : 0.f; h3 = h3 > 0.f ? h3 : 0.f;
      uint2 ph;
      ph.x = (uint32_t)f2bf(h0) | ((uint32_t)f2bf(h1) << 16);
      ph.y = (uint32_t)f2bf(h2) | ((uint32_t)f2bf(h3) << 16);
      *(uint2*)(slds + lrow * 256 + ((col0 * 2) ^ ((lrow & 15) << 4))) = ph;
    }
    __syncthreads();

    // full-line stores: 4 x (512 thr x 16B = 8KB) = 32KB tile
#pragma unroll
    for (int i = 0; i < 4; ++i) {
      const int ofs = i * 8192 + t * 16;
      const int trow = ofs >> 8;
      const int inrow = ofs & 255;
      const int grow = tile_m0 + trow;
      if (grow < NN)
        *(uint4*)(h + (size_t)grow * C + (inrow >> 1)) =
            *(const uint4*)(slds + (trow << 8) + (inrow ^ ((trow & 15) << 4)));
    }
  } else {
    // ---------------- phase1 role: bucket edges by dst>>7 ----------------
    int* bh = (int*)slds;                     // NB ints: histogram / cursor
    int* gb = bh + NB;                        // NB ints: reserved base
    const int blk = blockIdx.x - MB;
    const int base = blk * 6400;              // 1600 int4 per block

    for (int i = t; i < NB; i += 512) bh[i] = 0;

    const int4* ed4 = (const int4*)(edst + base);
    const int4* es4 = (const int4*)(esrc + base);
    int4 dv[4], sv[4];
    bool val[4];
#pragma unroll
    for (int k = 0; k < 4; ++k) {
      int i = t + k * 512;
      val[k] = (i < 1600);
      if (val[k]) { dv[k] = ed4[i]; sv[k] = es4[i]; }
    }
    __syncthreads();

#pragma unroll
    for (int k = 0; k < 4; ++k) if (val[k]) {
      atomicAdd(&bh[dv[k].x >> 7], 1); atomicAdd(&bh[dv[k].y >> 7], 1);
      atomicAdd(&bh[dv[k].z >> 7], 1); atomicAdd(&bh[dv[k].w >> 7], 1);
    }
    __syncthreads();

    for (int i = t; i < NB; i += 512) {
      int c = bh[i];
      gb[i] = c ? atomicAdd(&gcnt[i], c) : 0;
      bh[i] = 0;                              // reuse as local cursor
    }
    __syncthreads();

#define P1_SCATTER(d, s) do { \
      int bb = (d) >> 7; \
      int o = atomicAdd(&bh[bb], 1); \
      int pos = gb[bb] + o; \
      if (pos < CAP) ebuf[(size_t)bb * CAP + pos] = ((uint32_t)((d) & 127) << 17) | (uint32_t)(s); \
    } while (0)

#pragma unroll
    for (int k = 0; k < 4; ++k) if (val[k]) {
      P1_SCATTER(dv[k].x, sv[k].x); P1_SCATTER(dv[k].y, sv[k].y);
      P1_SCATTER(dv[k].z, sv[k].z); P1_SCATTER(dv[k].w, sv[k].w);
    }
#undef P1_SCATTER
  }
}

// ------- fused phase2 + aggregate: one block per bucket (1024 thr) ----------
// Sort bucket b in LDS (by local_dst, src-slice), then 16 waves aggregate the
// bucket's 128 nodes (8 nodes/wave), edge indices read from LDS (no global CSR).
__global__ __launch_bounds__(1024) void p2agg_k(
    const uint32_t* __restrict__ ebuf, const int* __restrict__ gcnt,
    const uint16_t* __restrict__ h, uint16_t* __restrict__ agg)
{
  __shared__ uint32_t raw[CAP];     // 16 KB
  __shared__ int lout[CAP];         // 16 KB  sorted src indices
  __shared__ int cnt2[128 * 16];    // 8 KB
  __shared__ int nd[128];
  __shared__ int sstart[128];
  __shared__ int sdegl[128];
  const int b = blockIdx.x, t = threadIdx.x;
  int cnt = gcnt[b]; if (cnt > CAP) cnt = CAP;

  for (int i = t; i < 128 * 16; i += 1024) cnt2[i] = 0;
  __syncthreads();
  for (int i = t; i < cnt; i += 1024) {
    uint32_t v = ebuf[(size_t)b * CAP + i];
    raw[i] = v;
    atomicAdd(&cnt2[(v >> 17) * 16 + ((v & 0x1FFFFu) >> SB_SHIFT)], 1);
  }
  __syncthreads();

  int deg_t = 0;
  if (t < 128) {
#pragma unroll
    for (int i = 0; i < 16; ++i) deg_t += cnt2[t * 16 + i];
    nd[t] = deg_t;
  }
  __syncthreads();
  for (int off = 1; off < 128; off <<= 1) {   // Hillis-Steele inclusive scan
    int v = 0;
    if (t < 128 && t >= off) v = nd[t - off];
    __syncthreads();
    if (t < 128) nd[t] += v;
    __syncthreads();
  }
  if (t < 128) {
    int pref = nd[t] - deg_t;                 // exclusive within bucket
    sstart[t] = pref; sdegl[t] = deg_t;
    int run = pref;
#pragma unroll
    for (int i = 0; i < 16; ++i) { int c = cnt2[t * 16 + i]; cnt2[t * 16 + i] = run; run += c; }
  }
  __syncthreads();
  for (int i = t; i < cnt; i += 1024) {
    uint32_t v = raw[i];
    int o = atomicAdd(&cnt2[(v >> 17) * 16 + ((v & 0x1FFFFu) >> SB_SHIFT)], 1);
    lout[o] = (int)(v & 0x1FFFFu);
  }
  __syncthreads();

  // ---- aggregate: wave w handles nodes w, w+16, ..., w+112 of this bucket --
  const int w = t >> 6, lane = t & 63;
  const int q = lane >> 4;            // edge slot 0..3
  const int l16 = lane & 15;          // channels l16*8 .. +7
  const size_t choff = (size_t)l16 * 8;

#define ACC8(v) do { \
    a0 += bf2x2((v).x); a1 += bf2x2((v).y); \
    a2 += bf2x2((v).z); a3 += bf2x2((v).w); \
  } while (0)

#pragma unroll 1
  for (int ni = 0; ni < 8; ++ni) {
    const int nl = w + ni * 16;               // 0..127
    const int node = b * 128 + nl;
    const int s0 = sstart[nl];
    const int cn = sdegl[nl];
    float2 a0 = {0.f, 0.f}, a1 = {0.f, 0.f}, a2 = {0.f, 0.f}, a3 = {0.f, 0.f};

    int j = 0;
    for (; j + 16 <= cn; j += 16) {
      int e0 = lout[s0 + j + q];
      int e1 = lout[s0 + j + 4 + q];
      int e2 = lout[s0 + j + 8 + q];
      int e3 = lout[s0 + j + 12 + q];
      uint4 v0 = *(const uint4*)(h + (size_t)e0 * C + choff);
      uint4 v1 = *(const uint4*)(h + (size_t)e1 * C + choff);
      uint4 v2 = *(const uint4*)(h + (size_t)e2 * C + choff);
      uint4 v3 = *(const uint4*)(h + (size_t)e3 * C + choff);
      ACC8(v0); ACC8(v1); ACC8(v2); ACC8(v3);
    }
    const int rem = cn - j;                   // 0..15 tail, clamped idx
    if (rem > 0) {
      int i0 = j + ((q      < rem) ? q      : 0);
      int i1 = j + ((q + 4  < rem) ? q + 4  : 0);
      int i2 = j + ((q + 8  < rem) ? q + 8  : 0);
      int i3 = j + ((q + 12 < rem) ? q + 12 : 0);
      int e0 = lout[s0 + i0];
      int e1 = lout[s0 + i1];
      int e2 = lout[s0 + i2];
      int e3 = lout[s0 + i3];
      uint4 v0 = *(const uint4*)(h + (size_t)e0 * C + choff);
      uint4 v1 = *(const uint4*)(h + (size_t)e1 * C + choff);
      uint4 v2 = *(const uint4*)(h + (size_t)e2 * C + choff);
      uint4 v3 = *(const uint4*)(h + (size_t)e3 * C + choff);
      if (q < rem)      ACC8(v0);
      if (q + 4 < rem)  ACC8(v1);
      if (q + 8 < rem)  ACC8(v2);
      if (q + 12 < rem) ACC8(v3);
    }

#pragma unroll
    for (int msk = 16; msk <= 32; msk <<= 1) {
      a0.x += __shfl_xor(a0.x, msk, 64); a0.y += __shfl_xor(a0.y, msk, 64);
      a1.x += __shfl_xor(a1.x, msk, 64); a1.y += __shfl_xor(a1.y, msk, 64);
      a2.x += __shfl_xor(a2.x, msk, 64); a2.y += __shfl_xor(a2.y, msk, 64);
      a3.x += __shfl_xor(a3.x, msk, 64); a3.y += __shfl_xor(a3.y, msk, 64);
    }
    if (q == 0 && node < NN) {
      uint4 p;
      p.x = (uint32_t)f2bf(a0.x) | ((uint32_t)f2bf(a0.y) << 16);
      p.y = (uint32_t)f2bf(a1.x) | ((uint32_t)f2bf(a1.y) << 16);
      p.z = (uint32_t)f2bf(a2.x) | ((uint32_t)f2bf(a2.y) << 16);
      p.w = (uint32_t)f2bf(a3.x) | ((uint32_t)f2bf(a3.y) << 16);
      *(uint4*)(agg + (size_t)node * C + choff) = p;
    }
  }
#undef ACC8
}

// ------- gemm_out: out = LN(agg@Wl^T + x@Wr^T + bl)*gamma + beta ------------
// Wl+Wr in 64KB LDS; x read as f32 and converted in-register.
__global__ __launch_bounds__(512) void gemm_out_k(
    const uint16_t* __restrict__ aggb, const float* __restrict__ x,
    const uint16_t* __restrict__ wlb, const uint16_t* __restrict__ wrb,
    const float* __restrict__ bl, const float* __restrict__ gamma,
    const float* __restrict__ beta, float* __restrict__ out)
{
  extern __shared__ uint8_t slds[];
  const int t = threadIdx.x;
#pragma unroll
  for (int qq = 0; qq < 8; ++qq) {            // stage Wl at 0, Wr at +32KB
    int ci = qq * 512 + t;                    // 0..4095
    int m  = ci >> 11;
    int cj = ci & 2047;
    int cl = cj >> 4, k16 = cj & 15;
    const uint16_t* wsrc = m == 0 ? wlb : wrb;
    *(short8*)(slds + m * 32768 + cl * 256 + ((k16 ^ (cl & 15)) << 4)) =
        *(const short8*)(wsrc + cj * 8);
  }
  __syncthreads();

  const int w = t >> 6, lane = t & 63;
  const int tile_m = blockIdx.x * 128 + w * 16;
  if (tile_m >= NN) return;
  const int r16 = lane & 15, g = lane >> 4;

  const int row = tile_m + r16;
  const int arow = row < NN ? row : NN - 1;   // clamp OOB read
  short8 a0[4], a1[4];
  const uint16_t* p0 = aggb + (size_t)arow * C + g * 8;
  const float* xp = x + (size_t)arow * C + g * 8;
#pragma unroll
  for (int kk = 0; kk < 4; ++kk) {
    a0[kk] = *(const short8*)(p0 + kk * 32);
    a1[kk] = cvt_row8(xp + kk * 32);
  }

  f32x4 acc[8];
  float s1 = 0.f, s2 = 0.f;
#pragma unroll
  for (int nt = 0; nt < 8; ++nt) {
    f32x4 c4 = {0.f, 0.f, 0.f, 0.f};
    const int c = nt * 16 + r16;
    const uint8_t* rbl = slds + c * 256;
    const uint8_t* rbr = slds + 32768 + c * 256;
#pragma unroll
    for (int kk = 0; kk < 4; ++kk) {
      int slot = (((kk << 2) + g) ^ (c & 15)) << 4;
      c4 = __builtin_amdgcn_mfma_f32_16x16x32_bf16(*(const short8*)(rbl + slot), a0[kk], c4, 0, 0, 0);
      c4 = __builtin_amdgcn_mfma_f32_16x16x32_bf16(*(const short8*)(rbr + slot), a1[kk], c4, 0, 0, 0);
    }
    const int col0 = nt * 16 + g * 4;
    float4 bl4 = *(const float4*)(bl + col0);
    c4[0] += bl4.x; c4[1] += bl4.y; c4[2] += bl4.z; c4[3] += bl4.w;
#pragma unroll
    for (int rr = 0; rr < 4; ++rr) { s1 += c4[rr]; s2 += c4[rr] * c4[rr]; }
    acc[nt] = c4;
  }

  // LN reduce across the 4 g-groups holding this row (lanes r16+16k)
  s1 += __shfl_xor(s1, 16, 64); s2 += __shfl_xor(s2, 16, 64);
  s1 += __shfl_xor(s1, 32, 64); s2 += __shfl_xor(s2, 32, 64);
  const float mean = s1 * (1.f / C);
  const float var = s2 * (1.f / C) - mean * mean;
  const float rstd = rsqrtf(var + 1e-5f);

  if (row < NN) {
#pragma unroll
    for (int nt = 0; nt < 8; ++nt) {
      const int col0 = nt * 16 + g * 4;
      float4 gm = *(const float4*)(gamma + col0);
      float4 bt = *(const float4*)(beta + col0);
      float4 o;
      o.x = (acc[nt][0] - mean) * rstd * gm.x + bt.x;
      o.y = (acc[nt][1] - mean) * rstd * gm.y + bt.y;
      o.z = (acc[nt][2] - mean) * rstd * gm.z + bt.z;
      o.w = (acc[nt][3] - mean) * rstd * gm.w + bt.w;
      *(float4*)(out + (size_t)row * C + col0) = o;   // 16B coalesced store
    }
  }
}

// ---------------- launch ----------------
extern "C" void kernel_launch(void* const* d_in, const int* in_sizes, int n_in,
                              void* d_out, int out_size, void* d_ws, size_t ws_size,
                              hipStream_t stream)
{
  const float* x        = (const float*)d_in[0];
  const int* ei         = (const int*)d_in[1];     // int32 from harness
  const float* Wp       = (const float*)d_in[2];
  const float* bp       = (const float*)d_in[3];
  const float* Wl       = (const float*)d_in[4];
  const float* bl       = (const float*)d_in[5];
  const float* Wr       = (const float*)d_in[6];
  const float* gamma    = (const float*)d_in[7];
  const float* beta     = (const float*)d_in[8];
  float* out            = (float*)d_out;

  char* ws = (char*)d_ws;
  // ws layout (no aliasing: p2agg reads ebuf while writing aggb) ~64.2 MB
  uint16_t* h    = (uint16_t*)(ws + 0);          // 25,600,000  relu(proj) bf16
  uint32_t* ebuf = (uint32_t*)(ws + 25600000);   // 12,812,288  bucketed edges
  uint16_t* aggb = (uint16_t*)(ws + 38412288);   // 25,600,000  agg bf16
  uint16_t* wpb  = (uint16_t*)(ws + 64012288);   // 32,768
  uint16_t* wlb  = (uint16_t*)(ws + 64045056);   // 32,768
  uint16_t* wrb  = (uint16_t*)(ws + 64077824);   // 32,768
  int* gcnt      = (int*)(ws + 64110592);        // 3,128

  const int* esrc = ei;        // edge_index[0]
  const int* edst = ei + NE;   // edge_index[1]

  hipMemsetAsync(gcnt, 0, NB * sizeof(int), stream);

  cast3_k<<<48, 256, 0, stream>>>(Wp, Wl, Wr, wpb, wlb, wrb);

  fused_front_k<<<MB + P1B, 512, 32768, stream>>>(
      x, wpb, bp, h, esrc, edst, gcnt, ebuf);

  p2agg_k<<<NB, 1024, 0, stream>>>(ebuf, gcnt, h, aggb);

  gemm_out_k<<<MBO, 512, 65536, stream>>>(aggb, x, wlb, wrb, bl, gamma, beta, out);
}